// Round 6
// baseline (565.744 us; speedup 1.0000x reference)
//
#include <hip/hip_runtime.h>

// PatchMatch propagation, B=2, H=W=64, corr (B,H,W,H,W) f32.
// Anti-diagonal wavefront, one wave per batch; lane r owns sweep-row r.
// R6: R5's 3-way speculative prefetch (proven bit-exact) with the register
// problem fixed: 256-thread block (__launch_bounds__(256,1) -> 512 VGPR cap)
// and banks as flat named scalars via macros (no lambdas/aggregates) so the
// two speculation banks live entirely in VGPRs. The taps for step d+1 are
// loaded during step d under all 3 possible carries; a 2-bit selector picks
// them -> global-load latency leaves the 508-step dependent chain.

struct __attribute__((packed, aligned(4))) f2u { float x, y; };

__device__ __forceinline__ float clamp63(float v) {
    return fminf(fmaxf(v, 0.0f), 63.0f);
}

__device__ __forceinline__ float sel3f(int s, float a0, float a1, float a2) {
    float r = (s == 1) ? a1 : a0;
    return (s == 2) ? a2 : r;
}

// Full bilinear sample (init / random-search), bit-exact vs reference.
__device__ __forceinline__ float bsample(const float* __restrict__ m, float x, float y) {
    float x0f = floorf(x), y0f = floorf(y);
    float wx1 = __fsub_rn(x, x0f);
    float wy1 = __fsub_rn(y, y0f);
    float wx0 = __fsub_rn(1.0f, wx1);
    float wy0 = __fsub_rn(1.0f, wy1);
    int x0 = (int)x0f, y0 = (int)y0f;
    int x1 = x0 + 1, y1 = y0 + 1;
    int y1c = min(y1, 63);
    int bx = min(x0, 62);
    f2u p0 = *(const f2u*)(m + y0 * 64 + bx);
    f2u p1 = *(const f2u*)(m + y1c * 64 + bx);
    bool hi = (x0 > 62);
    float v00 = hi ? p0.y : p0.x;
    float v10 = (x1 <= 63) ? p0.y : 0.0f;
    float v01 = hi ? p1.y : p1.x;
    v01 = (y1 <= 63) ? v01 : 0.0f;
    float v11 = ((x1 <= 63) && (y1 <= 63)) ? p1.y : 0.0f;
    float t0 = __fmul_rn(__fmul_rn(wx0, wy0), v00);
    float t1 = __fmul_rn(__fmul_rn(wx1, wy0), v10);
    float t2 = __fmul_rn(__fmul_rn(wx0, wy1), v01);
    float t3 = __fmul_rn(__fmul_rn(wx1, wy1), v11);
    return __fadd_rn(__fadd_rn(__fadd_rn(t0, t1), t2), t3);
}

// Score from pre-loaded pair taps (loaded at bx=min(floor(x),62),
// rows floor(y), min(floor(y)+1,63) of the SAME coords). Bit-exact.
__device__ __forceinline__ float score_taps(float x, float y, f2u p0, f2u p1) {
    float x0f = floorf(x), y0f = floorf(y);
    float wx1 = __fsub_rn(x, x0f);
    float wy1 = __fsub_rn(y, y0f);
    float wx0 = __fsub_rn(1.0f, wx1);
    float wy0 = __fsub_rn(1.0f, wy1);
    int x0 = (int)x0f, y0 = (int)y0f;
    int x1 = x0 + 1, y1 = y0 + 1;
    bool hi = (x0 > 62);
    float v00 = hi ? p0.y : p0.x;
    float v10 = (x1 <= 63) ? p0.y : 0.0f;
    float v01 = hi ? p1.y : p1.x;
    v01 = (y1 <= 63) ? v01 : 0.0f;
    float v11 = ((x1 <= 63) && (y1 <= 63)) ? p1.y : 0.0f;
    float t0 = __fmul_rn(__fmul_rn(wx0, wy0), v00);
    float t1 = __fmul_rn(__fmul_rn(wx1, wy0), v10);
    float t2 = __fmul_rn(__fmul_rn(wx0, wy1), v01);
    float t3 = __fmul_rn(__fmul_rn(wx1, wy1), v11);
    return __fadd_rn(__fadd_rn(__fadd_rn(t0, t1), t2), t3);
}

__device__ __forceinline__ void tapload(const float* __restrict__ m, float x, float y,
                                        f2u& A, f2u& B) {
    int x0 = (int)floorf(x);
    int y0 = (int)floorf(y);
    int bx = min(x0, 62);
    int y1c = min(y0 + 1, 63);
    A = *(const f2u*)(m + y0 * 64 + bx);
    B = *(const f2u*)(m + y1c * 64 + bx);
}

// Declare one speculation bank as flat scalars with suffix S.
#define BANK_DECL(S) \
    float pnx##S, pny##S, pns##S; \
    float hx0##S, hy0##S, hx1##S, hy1##S, hx2##S, hy2##S; \
    float vx0##S, vy0##S, vx1##S, vy1##S, vx2##S, vy2##S; \
    f2u hA0##S, hB0##S, hA1##S, hB1##S, hA2##S, hB2##S; \
    f2u vA0##S, vB0##S, vA1##S, vB1##S, vA2##S, vB2##S;

// Prefetch bank OUT for diagonal step dnext (pixel c = dnext - r), given this
// lane's 3 possible carries K = {(kx0,ky0),(kx1,ky1),(kx2,ky2)} = {p, v, h}.
#define PREFETCH(dnext, kx0, ky0, kx1, ky1, kx2, ky2, OUT) { \
    float nx0 = __shfl_up((kx0), 1), ny0 = __shfl_up((ky0), 1); \
    float nx1 = __shfl_up((kx1), 1), ny1 = __shfl_up((ky1), 1); \
    float nx2 = __shfl_up((kx2), 1), ny2 = __shfl_up((ky2), 1); \
    hx0##OUT = clamp63(__fadd_rn((kx0), fdx)); hy0##OUT = clamp63((ky0)); \
    hx1##OUT = clamp63(__fadd_rn((kx1), fdx)); hy1##OUT = clamp63((ky1)); \
    hx2##OUT = clamp63(__fadd_rn((kx2), fdx)); hy2##OUT = clamp63((ky2)); \
    vx0##OUT = clamp63(nx0); vy0##OUT = clamp63(__fadd_rn(ny0, fdy)); \
    vx1##OUT = clamp63(nx1); vy1##OUT = clamp63(__fadd_rn(ny1, fdy)); \
    vx2##OUT = clamp63(nx2); vy2##OUT = clamp63(__fadd_rn(ny2, fdy)); \
    const int cn_ = (dnext) - r; \
    const int ccn_ = min(max(cn_, 0), 63); \
    const int jn_ = dxpos ? ccn_ : 63 - ccn_; \
    if ((cn_ >= 0) && (cn_ < 64)) { \
        const int pn_ = i * 64 + jn_; \
        pnx##OUT = lx[pn_]; pny##OUT = ly[pn_]; pns##OUT = ls[pn_]; \
        const float* m_ = rowbase + (size_t)jn_ * 4096; \
        tapload(m_, hx0##OUT, hy0##OUT, hA0##OUT, hB0##OUT); \
        tapload(m_, hx1##OUT, hy1##OUT, hA1##OUT, hB1##OUT); \
        tapload(m_, hx2##OUT, hy2##OUT, hA2##OUT, hB2##OUT); \
        tapload(m_, vx0##OUT, vy0##OUT, vA0##OUT, vB0##OUT); \
        tapload(m_, vx1##OUT, vy1##OUT, vA1##OUT, vB1##OUT); \
        tapload(m_, vx2##OUT, vy2##OUT, vA2##OUT, vB2##OUT); \
    } else { \
        pnx##OUT = 0.0f; pny##OUT = 0.0f; pns##OUT = 0.0f; \
    } \
}

// One diagonal step d: resolve pixel (r, d-r) from bank IN, prefetch bank OUT.
#define STEP(d_, IN, OUT) { \
    const int c = (d_) - r; \
    const bool act = (c >= 0) && (c < 64); \
    const int cc = min(max(c, 0), 63); \
    const int j = dxpos ? cc : 63 - cc; \
    const int p = i * 64 + j; \
    int snb = __shfl_up(sme, 1); \
    float hcx = sel3f(sme, hx0##IN, hx1##IN, hx2##IN); \
    float hcy = sel3f(sme, hy0##IN, hy1##IN, hy2##IN); \
    float vcx = sel3f(snb, vx0##IN, vx1##IN, vx2##IN); \
    float vcy = sel3f(snb, vy0##IN, vy1##IN, vy2##IN); \
    float px = pnx##IN, py = pny##IN, ps = pns##IN; \
    PREFETCH((d_) + 1, px, py, vcx, vcy, hcx, hcy, OUT); \
    if (act) { \
        f2u HA, HB, VA, VB; \
        HA.x = sel3f(sme, hA0##IN.x, hA1##IN.x, hA2##IN.x); \
        HA.y = sel3f(sme, hA0##IN.y, hA1##IN.y, hA2##IN.y); \
        HB.x = sel3f(sme, hB0##IN.x, hB1##IN.x, hB2##IN.x); \
        HB.y = sel3f(sme, hB0##IN.y, hB1##IN.y, hB2##IN.y); \
        VA.x = sel3f(snb, vA0##IN.x, vA1##IN.x, vA2##IN.x); \
        VA.y = sel3f(snb, vA0##IN.y, vA1##IN.y, vA2##IN.y); \
        VB.x = sel3f(snb, vB0##IN.x, vB1##IN.x, vB2##IN.x); \
        VB.y = sel3f(snb, vB0##IN.y, vB1##IN.y, vB2##IN.y); \
        float hs = score_taps(hcx, hcy, HA, HB); \
        float vs = score_taps(vcx, vcy, VA, VB); \
        bool uv = (vs > ps) && (r > 0); \
        float ux = uv ? vcx : px; \
        float uy = uv ? vcy : py; \
        float us = uv ? vs : ps; \
        bool uh = (hs > us) && (c > 0); \
        float fx = uh ? hcx : ux; \
        float fy = uh ? hcy : uy; \
        float fs = uh ? hs : us; \
        sme = uh ? 2 : (uv ? 1 : 0); \
        lx[p] = fx; ly[p] = fy; ls[p] = fs; \
    } \
}

__global__ __launch_bounds__(256, 1) void MatchingPropagator_65180423685702_kernel(
        const float* __restrict__ raw,    // (B,2,64,64)
        const float* __restrict__ corr,   // (B,64,64,64,64)
        const float* __restrict__ noise,  // (3,B,64,64,2)
        float* __restrict__ out) {        // (B,2,64,64)
    const int b = blockIdx.x;
    const float* __restrict__ corrb = corr + (size_t)b * 64 * 64 * 4096;
    const int tid = threadIdx.x;

    __shared__ float lx[4096];
    __shared__ float ly[4096];
    __shared__ float ls[4096];

    // init: coords + memoized scores (parallel; TA-throughput-bound)
    for (int p = tid; p < 4096; p += 256) {
        float x = raw[(size_t)b * 8192 + p];
        float y = raw[(size_t)b * 8192 + 4096 + p];
        lx[p] = x; ly[p] = y;
        ls[p] = bsample(corrb + (size_t)p * 4096, x, y);
    }
    __syncthreads();

    const int dys[4] = {1, -1, -1, 1};
    const int dxs[4] = {1, -1, 1, -1};

#pragma unroll
    for (int k = 0; k < 4; ++k) {
        const int dy = dys[k], dx = dxs[k];
        const float fdy = (float)dy, fdx = (float)dx;
        const bool dxpos = (dx > 0);

        if (tid < 64) {
            const int r = tid;
            const int i = (dy > 0) ? r : 63 - r;
            const float* rowbase = corrb + (size_t)i * 64 * 4096;
            int sme = 0;
            BANK_DECL(_A)
            BANK_DECL(_B)

            // prologue: bank A for d=0 with K = {(0,0)}x3 (initial carries)
            PREFETCH(0, 0.0f, 0.0f, 0.0f, 0.0f, 0.0f, 0.0f, _A);

#pragma unroll 1
            for (int d = 0; d < 128; d += 2) {
                STEP(d, _A, _B);
                STEP(d + 1, _B, _A);
            }
        }
        __syncthreads();

        // random search (elementwise, all 256 threads)
        if (k < 3) {
            const float* nz = noise + ((size_t)k * 2 + b) * 8192;
            for (int p = tid; p < 4096; p += 256) {
                float x = lx[p], y = ly[p], s = ls[p];
                float ex = nz[p * 2 + 0], ey = nz[p * 2 + 1];
                float nx = fmaxf(__fadd_rn(x, __fmul_rn(3.0f, ex)), 0.0f);
                float ny = fmaxf(__fadd_rn(y, __fmul_rn(3.0f, ey)), 0.0f);
                // faithful reference oddity: boundary hit overwrites BOTH channels
                if (nx >= 64.0f) { nx = 63.0f; ny = 63.0f; }
                if (ny >= 64.0f) { nx = 63.0f; ny = 63.0f; }
                float ns = bsample(corrb + (size_t)p * 4096, nx, ny);
                if (ns > __fmul_rn(1.05f, s)) {
                    lx[p] = nx; ly[p] = ny; ls[p] = ns;
                }
            }
            __syncthreads();
        }
    }

    // output: (B,2,H,W)
    for (int p = tid; p < 4096; p += 256) {
        out[(size_t)b * 8192 + p] = lx[p];
        out[(size_t)b * 8192 + 4096 + p] = ly[p];
    }
}

extern "C" void kernel_launch(void* const* d_in, const int* in_sizes, int n_in,
                              void* d_out, int out_size, void* d_ws, size_t ws_size,
                              hipStream_t stream) {
    const float* raw   = (const float*)d_in[0];
    const float* corr  = (const float*)d_in[1];
    const float* noise = (const float*)d_in[2];
    float* out = (float*)d_out;
    (void)in_sizes; (void)n_in; (void)out_size; (void)d_ws; (void)ws_size;
    MatchingPropagator_65180423685702_kernel<<<2, 256, 0, stream>>>(raw, corr, noise, out);
}

// Round 7
// 552.292 us; speedup vs baseline: 1.0244x; 1.0244x over previous
//
#include <hip/hip_runtime.h>

// PatchMatch propagation, B=2, H=W=64, corr (B,H,W,H,W) f32.
// Anti-diagonal wavefront, one wave per batch; lane r owns sweep-row r.
// R7: sweep wave is EXACTLY R4's proven chain (4 pair-loads, 2 shfls/step).
// Waves 1-3 are PREFETCHERS: using finals through diag d-1 (published via a
// volatile LDS progress word), they compute all 3 possible carries of each
// diag-(d+1) pixel and touch the corresponding candidate tap lines ~1 step
// early -> the sweep's dependent loads become L1/L2 hits instead of L3
// round-trips. Prefetch reads race benignly (coords always in [0,63]).

struct __attribute__((packed, aligned(4))) f2u { float x, y; };

__device__ __forceinline__ float clamp63(float v) {
    return fminf(fmaxf(v, 0.0f), 63.0f);
}

// Full bilinear sample (init / random-search), bit-exact vs reference.
__device__ __forceinline__ float bsample(const float* __restrict__ m, float x, float y) {
    float x0f = floorf(x), y0f = floorf(y);
    float wx1 = __fsub_rn(x, x0f);
    float wy1 = __fsub_rn(y, y0f);
    float wx0 = __fsub_rn(1.0f, wx1);
    float wy0 = __fsub_rn(1.0f, wy1);
    int x0 = (int)x0f, y0 = (int)y0f;
    int x1 = x0 + 1, y1 = y0 + 1;
    int y1c = min(y1, 63);
    int bx = min(x0, 62);
    f2u p0 = *(const f2u*)(m + y0 * 64 + bx);
    f2u p1 = *(const f2u*)(m + y1c * 64 + bx);
    bool hi = (x0 > 62);
    float v00 = hi ? p0.y : p0.x;
    float v10 = (x1 <= 63) ? p0.y : 0.0f;
    float v01 = hi ? p1.y : p1.x;
    v01 = (y1 <= 63) ? v01 : 0.0f;
    float v11 = ((x1 <= 63) && (y1 <= 63)) ? p1.y : 0.0f;
    float t0 = __fmul_rn(__fmul_rn(wx0, wy0), v00);
    float t1 = __fmul_rn(__fmul_rn(wx1, wy0), v10);
    float t2 = __fmul_rn(__fmul_rn(wx0, wy1), v01);
    float t3 = __fmul_rn(__fmul_rn(wx1, wy1), v11);
    return __fadd_rn(__fadd_rn(__fadd_rn(t0, t1), t2), t3);
}

__global__ __launch_bounds__(256, 1) void MatchingPropagator_65180423685702_kernel(
        const float* __restrict__ raw,    // (B,2,64,64)
        const float* __restrict__ corr,   // (B,64,64,64,64)
        const float* __restrict__ noise,  // (3,B,64,64,2)
        float* __restrict__ out) {        // (B,2,64,64)
    const int b = blockIdx.x;
    const float* __restrict__ corrb = corr + (size_t)b * 64 * 64 * 4096;
    const int tid = threadIdx.x;
    const int wid = tid >> 6;
    const int lane = tid & 63;

    __shared__ float lx[4096];
    __shared__ float ly[4096];
    __shared__ float ls[4096];
    __shared__ volatile int prog;   // last completed diagonal of current sweep

    // init: coords + memoized scores (parallel)
    for (int p = tid; p < 4096; p += 256) {
        float x = raw[(size_t)b * 8192 + p];
        float y = raw[(size_t)b * 8192 + 4096 + p];
        lx[p] = x; ly[p] = y;
        ls[p] = bsample(corrb + (size_t)p * 4096, x, y);
    }
    __syncthreads();

    const int dys[4] = {1, -1, -1, 1};
    const int dxs[4] = {1, -1, 1, -1};

#pragma unroll
    for (int k = 0; k < 4; ++k) {
        const int dy = dys[k], dx = dxs[k];
        const float fdy = (float)dy, fdx = (float)dx;
        const bool dxpos = (dx > 0);

        if (tid == 0) prog = -1;
        __syncthreads();

        if (wid == 0) {
            // ================= SWEEP WAVE — R4's proven chain =================
            const int r = lane;
            const int i = (dy > 0) ? r : 63 - r;
            const float* rowbase = corrb + (size_t)i * 64 * 4096;
            float cx = 0.0f, cy = 0.0f;
            for (int d = 0; d < 127; ++d) {
                float vnx = __shfl_up(cx, 1);
                float vny = __shfl_up(cy, 1);
                const int c = d - r;
                if (c >= 0 && c < 64) {
                    const int j = dxpos ? c : 63 - c;
                    const int p = i * 64 + j;
                    const float* m = rowbase + (size_t)j * 4096;
                    float px = lx[p], py = ly[p], ps = ls[p];
                    float vcx = clamp63(vnx);
                    float vcy = clamp63(__fadd_rn(vny, fdy));
                    float hcx = clamp63(__fadd_rn(cx, fdx));
                    float hcy = clamp63(cy);
                    float vx0f = floorf(vcx), vy0f = floorf(vcy);
                    float hx0f = floorf(hcx), hy0f = floorf(hcy);
                    int vx0 = (int)vx0f, vy0 = (int)vy0f;
                    int hx0 = (int)hx0f, hy0 = (int)hy0f;
                    int vx1 = vx0 + 1, vy1 = vy0 + 1;
                    int hx1 = hx0 + 1, hy1 = hy0 + 1;
                    int vy1c = min(vy1, 63), hy1c = min(hy1, 63);
                    int vbx = min(vx0, 62), hbx = min(hx0, 62);
                    f2u A0 = *(const f2u*)(m + vy0 * 64 + vbx);
                    f2u A1 = *(const f2u*)(m + vy1c * 64 + vbx);
                    f2u B0 = *(const f2u*)(m + hy0 * 64 + hbx);
                    f2u B1 = *(const f2u*)(m + hy1c * 64 + hbx);
                    float vwx1 = __fsub_rn(vcx, vx0f), vwy1 = __fsub_rn(vcy, vy0f);
                    float vwx0 = __fsub_rn(1.0f, vwx1), vwy0 = __fsub_rn(1.0f, vwy1);
                    float hwx1 = __fsub_rn(hcx, hx0f), hwy1 = __fsub_rn(hcy, hy0f);
                    float hwx0 = __fsub_rn(1.0f, hwx1), hwy0 = __fsub_rn(1.0f, hwy1);
                    float vw00 = __fmul_rn(vwx0, vwy0), vw10 = __fmul_rn(vwx1, vwy0);
                    float vw01 = __fmul_rn(vwx0, vwy1), vw11 = __fmul_rn(vwx1, vwy1);
                    float hw00 = __fmul_rn(hwx0, hwy0), hw10 = __fmul_rn(hwx1, hwy0);
                    float hw01 = __fmul_rn(hwx0, hwy1), hw11 = __fmul_rn(hwx1, hwy1);
                    bool vhi = (vx0 > 62), hhi = (hx0 > 62);
                    float a00 = vhi ? A0.y : A0.x;
                    float a10 = (vx1 <= 63) ? A0.y : 0.0f;
                    float a01 = vhi ? A1.y : A1.x;
                    a01 = (vy1 <= 63) ? a01 : 0.0f;
                    float a11 = ((vx1 <= 63) && (vy1 <= 63)) ? A1.y : 0.0f;
                    float b00 = hhi ? B0.y : B0.x;
                    float b10 = (hx1 <= 63) ? B0.y : 0.0f;
                    float b01 = hhi ? B1.y : B1.x;
                    b01 = (hy1 <= 63) ? b01 : 0.0f;
                    float b11 = ((hx1 <= 63) && (hy1 <= 63)) ? B1.y : 0.0f;
                    float vs = __fadd_rn(__fadd_rn(__fadd_rn(
                                   __fmul_rn(vw00, a00), __fmul_rn(vw10, a10)),
                                   __fmul_rn(vw01, a01)), __fmul_rn(vw11, a11));
                    float hs = __fadd_rn(__fadd_rn(__fadd_rn(
                                   __fmul_rn(hw00, b00), __fmul_rn(hw10, b10)),
                                   __fmul_rn(hw01, b01)), __fmul_rn(hw11, b11));
                    bool uv = (vs > ps) && (r > 0);
                    float ux = uv ? vcx : px;
                    float uy = uv ? vcy : py;
                    float us = uv ? vs : ps;
                    bool uh = (hs > us) && (c > 0);
                    cx = uh ? hcx : ux;
                    cy = uh ? hcy : uy;
                    float fs = uh ? hs : us;
                    lx[p] = cx; ly[p] = cy; ls[p] = fs;
                }
                if (lane == 0) prog = d;   // publish progress (hint-quality)
            }
        } else {
            // ================= PREFETCH WAVES (carry hypothesis sel) ==========
            const int sel = wid - 1;            // 0=p-carry, 1=v-carry, 2=h-carry
            const int r = lane;
            const int i = (dy > 0) ? r : 63 - r;
            const float* rowbase = corrb + (size_t)i * 64 * 4096;

#pragma unroll 1
            for (int t = 0; t < 126; ++t) {
                // need finals through diagonal t-1
                while (prog < t - 1) __builtin_amdgcn_s_sleep(2);
                const int cp = t + 1 - r;       // my pixel on diagonal t+1
                if (cp >= 0 && cp < 64) {
                    // read sweep-space state with clamped indices (benign races)
                    auto readst = [&](int rr, int cc, float& x, float& y) {
                        rr = min(max(rr, 0), 63); cc = min(max(cc, 0), 63);
                        int ii = (dy > 0) ? rr : 63 - rr;
                        int jj = dxpos ? cc : 63 - cc;
                        int pp = ii * 64 + jj;
                        x = lx[pp]; y = ly[pp];
                    };
                    float kx, ky, nx, ny, ax, ay;
                    if (sel == 0) {
                        readst(r, cp - 1, kx, ky);
                        readst(r - 1, cp, nx, ny);
                    } else if (sel == 1) {
                        readst(r - 1, cp - 1, ax, ay);
                        kx = clamp63(ax); ky = clamp63(__fadd_rn(ay, fdy));
                        readst(r - 2, cp, ax, ay);
                        nx = clamp63(ax); ny = clamp63(__fadd_rn(ay, fdy));
                    } else {
                        readst(r, cp - 2, ax, ay);
                        kx = clamp63(__fadd_rn(ax, fdx)); ky = clamp63(ay);
                        readst(r - 1, cp - 1, ax, ay);
                        nx = clamp63(__fadd_rn(ax, fdx)); ny = clamp63(ay);
                    }
                    // candidate positions under this hypothesis
                    float hx = clamp63(__fadd_rn(kx, fdx)), hy = clamp63(ky);
                    float vx = clamp63(nx), vy = clamp63(__fadd_rn(ny, fdy));
                    const int j = dxpos ? cp : 63 - cp;
                    const float* m = rowbase + (size_t)j * 4096;
                    // touch the 4 pair-lines (forced live, no false chains)
                    {
                        int x0 = (int)floorf(hx), y0 = (int)floorf(hy);
                        int bx = min(x0, 62), y1c = min(y0 + 1, 63);
                        f2u A = *(const f2u*)(m + y0 * 64 + bx);
                        f2u B = *(const f2u*)(m + y1c * 64 + bx);
                        asm volatile("" :: "v"(A.x), "v"(A.y), "v"(B.x), "v"(B.y));
                    }
                    {
                        int x0 = (int)floorf(vx), y0 = (int)floorf(vy);
                        int bx = min(x0, 62), y1c = min(y0 + 1, 63);
                        f2u A = *(const f2u*)(m + y0 * 64 + bx);
                        f2u B = *(const f2u*)(m + y1c * 64 + bx);
                        asm volatile("" :: "v"(A.x), "v"(A.y), "v"(B.x), "v"(B.y));
                    }
                }
            }
        }
        __syncthreads();

        // random search (elementwise, all 256 threads)
        if (k < 3) {
            const float* nz = noise + ((size_t)k * 2 + b) * 8192;
            for (int p = tid; p < 4096; p += 256) {
                float x = lx[p], y = ly[p], s = ls[p];
                float ex = nz[p * 2 + 0], ey = nz[p * 2 + 1];
                float nx = fmaxf(__fadd_rn(x, __fmul_rn(3.0f, ex)), 0.0f);
                float ny = fmaxf(__fadd_rn(y, __fmul_rn(3.0f, ey)), 0.0f);
                // faithful reference oddity: boundary hit overwrites BOTH channels
                if (nx >= 64.0f) { nx = 63.0f; ny = 63.0f; }
                if (ny >= 64.0f) { nx = 63.0f; ny = 63.0f; }
                float ns = bsample(corrb + (size_t)p * 4096, nx, ny);
                if (ns > __fmul_rn(1.05f, s)) {
                    lx[p] = nx; ly[p] = ny; ls[p] = ns;
                }
            }
            __syncthreads();
        }
    }

    // output: (B,2,H,W)
    for (int p = tid; p < 4096; p += 256) {
        out[(size_t)b * 8192 + p] = lx[p];
        out[(size_t)b * 8192 + 4096 + p] = ly[p];
    }
}

extern "C" void kernel_launch(void* const* d_in, const int* in_sizes, int n_in,
                              void* d_out, int out_size, void* d_ws, size_t ws_size,
                              hipStream_t stream) {
    const float* raw   = (const float*)d_in[0];
    const float* corr  = (const float*)d_in[1];
    const float* noise = (const float*)d_in[2];
    float* out = (float*)d_out;
    (void)in_sizes; (void)n_in; (void)out_size; (void)d_ws; (void)ws_size;
    MatchingPropagator_65180423685702_kernel<<<2, 256, 0, stream>>>(raw, corr, noise, out);
}

// Round 8
// 434.856 us; speedup vs baseline: 1.3010x; 1.2701x over previous
//
#include <hip/hip_runtime.h>

// PatchMatch propagation, B=2, H=W=64, corr (B,H,W,H,W) f32.
// Anti-diagonal wavefront, one wave per batch; lane r owns sweep-row r.
// R8: in-wave 3-way speculative prefetch (R6's proven-bit-exact algebra) with
// the schedule PINNED: per step, phase A issues ALL 12 next-step paired tap
// loads (unconditional, clamped addresses -> uniform vmcnt), then
// sched_barrier(0), then phase B consumes the PREVIOUS step's taps. The
// barrier stops the compiler sinking the issue below the consume, so the
// waitcnt pass emits a counted vmcnt and loads age one full step.
// T = work + max(0, L - T) ~ (1200+500)/2 ~ 850 cy/step (vs R4's 1490).

struct __attribute__((packed, aligned(4))) f2u { float x, y; };

__device__ __forceinline__ float clamp63(float v) {
    return fminf(fmaxf(v, 0.0f), 63.0f);
}

__device__ __forceinline__ float sel3f(int s, float a0, float a1, float a2) {
    float r = (s == 1) ? a1 : a0;
    return (s == 2) ? a2 : r;
}

// Full bilinear sample (init / random-search), bit-exact vs reference.
__device__ __forceinline__ float bsample(const float* __restrict__ m, float x, float y) {
    float x0f = floorf(x), y0f = floorf(y);
    float wx1 = __fsub_rn(x, x0f);
    float wy1 = __fsub_rn(y, y0f);
    float wx0 = __fsub_rn(1.0f, wx1);
    float wy0 = __fsub_rn(1.0f, wy1);
    int x0 = (int)x0f, y0 = (int)y0f;
    int x1 = x0 + 1, y1 = y0 + 1;
    int y1c = min(y1, 63);
    int bx = min(x0, 62);
    f2u p0 = *(const f2u*)(m + y0 * 64 + bx);
    f2u p1 = *(const f2u*)(m + y1c * 64 + bx);
    bool hi = (x0 > 62);
    float v00 = hi ? p0.y : p0.x;
    float v10 = (x1 <= 63) ? p0.y : 0.0f;
    float v01 = hi ? p1.y : p1.x;
    v01 = (y1 <= 63) ? v01 : 0.0f;
    float v11 = ((x1 <= 63) && (y1 <= 63)) ? p1.y : 0.0f;
    float t0 = __fmul_rn(__fmul_rn(wx0, wy0), v00);
    float t1 = __fmul_rn(__fmul_rn(wx1, wy0), v10);
    float t2 = __fmul_rn(__fmul_rn(wx0, wy1), v01);
    float t3 = __fmul_rn(__fmul_rn(wx1, wy1), v11);
    return __fadd_rn(__fadd_rn(__fadd_rn(t0, t1), t2), t3);
}

// Score from pre-loaded pair taps (loaded at bx=min(floor(x),62),
// rows floor(y), min(floor(y)+1,63) of the SAME coords). Bit-exact.
__device__ __forceinline__ float score_taps(float x, float y, f2u p0, f2u p1) {
    float x0f = floorf(x), y0f = floorf(y);
    float wx1 = __fsub_rn(x, x0f);
    float wy1 = __fsub_rn(y, y0f);
    float wx0 = __fsub_rn(1.0f, wx1);
    float wy0 = __fsub_rn(1.0f, wy1);
    int x0 = (int)x0f, y0 = (int)y0f;
    int x1 = x0 + 1, y1 = y0 + 1;
    bool hi = (x0 > 62);
    float v00 = hi ? p0.y : p0.x;
    float v10 = (x1 <= 63) ? p0.y : 0.0f;
    float v01 = hi ? p1.y : p1.x;
    v01 = (y1 <= 63) ? v01 : 0.0f;
    float v11 = ((x1 <= 63) && (y1 <= 63)) ? p1.y : 0.0f;
    float t0 = __fmul_rn(__fmul_rn(wx0, wy0), v00);
    float t1 = __fmul_rn(__fmul_rn(wx1, wy0), v10);
    float t2 = __fmul_rn(__fmul_rn(wx0, wy1), v01);
    float t3 = __fmul_rn(__fmul_rn(wx1, wy1), v11);
    return __fadd_rn(__fadd_rn(__fadd_rn(t0, t1), t2), t3);
}

__device__ __forceinline__ void tapload(const float* __restrict__ m, float x, float y,
                                        f2u& A, f2u& B) {
    int x0 = (int)floorf(x);
    int y0 = (int)floorf(y);
    int bx = min(x0, 62);
    int y1c = min(y0 + 1, 63);
    A = *(const f2u*)(m + y0 * 64 + bx);
    B = *(const f2u*)(m + y1c * 64 + bx);
}

// One speculation bank as flat named scalars (suffix S). Hyp order {p,v,h}.
#define BANK_DECL(S) \
    float pnx##S, pny##S, pns##S; \
    float hx0##S, hy0##S, hx1##S, hy1##S, hx2##S, hy2##S; \
    float vx0##S, vy0##S, vx1##S, vy1##S, vx2##S, vy2##S; \
    f2u hA0##S, hB0##S, hA1##S, hB1##S, hA2##S, hB2##S; \
    f2u vA0##S, vB0##S, vA1##S, vB1##S, vA2##S, vB2##S;

// Issue next-step speculative loads, UNCONDITIONAL (clamped pixel index so
// every step issues exactly 12 loads -> uniform outstanding-count).
#define PREFETCH(dnext, OUT, kpx, kpy, kvx, kvy, khx, khy) { \
    float n0x = __shfl_up((kpx), 1), n0y = __shfl_up((kpy), 1); \
    float n1x = __shfl_up((kvx), 1), n1y = __shfl_up((kvy), 1); \
    float n2x = __shfl_up((khx), 1), n2y = __shfl_up((khy), 1); \
    hx0##OUT = clamp63(__fadd_rn((kpx), fdx)); hy0##OUT = clamp63((kpy)); \
    hx1##OUT = clamp63(__fadd_rn((kvx), fdx)); hy1##OUT = clamp63((kvy)); \
    hx2##OUT = clamp63(__fadd_rn((khx), fdx)); hy2##OUT = clamp63((khy)); \
    vx0##OUT = clamp63(n0x); vy0##OUT = clamp63(__fadd_rn(n0y, fdy)); \
    vx1##OUT = clamp63(n1x); vy1##OUT = clamp63(__fadd_rn(n1y, fdy)); \
    vx2##OUT = clamp63(n2x); vy2##OUT = clamp63(__fadd_rn(n2y, fdy)); \
    const int cn_ = min(max((dnext) - r, 0), 63); \
    const int jn_ = dxpos ? cn_ : 63 - cn_; \
    const int pn_ = i * 64 + jn_; \
    pnx##OUT = lx[pn_]; pny##OUT = ly[pn_]; pns##OUT = ls[pn_]; \
    const float* m_ = rowbase + (size_t)jn_ * 4096; \
    tapload(m_, hx0##OUT, hy0##OUT, hA0##OUT, hB0##OUT); \
    tapload(m_, hx1##OUT, hy1##OUT, hA1##OUT, hB1##OUT); \
    tapload(m_, hx2##OUT, hy2##OUT, hA2##OUT, hB2##OUT); \
    tapload(m_, vx0##OUT, vy0##OUT, vA0##OUT, vB0##OUT); \
    tapload(m_, vx1##OUT, vy1##OUT, vA1##OUT, vB1##OUT); \
    tapload(m_, vx2##OUT, vy2##OUT, vA2##OUT, vB2##OUT); \
}

// One diagonal step: phase A (resolve coords + issue OUT) | barrier |
// phase B (consume IN taps, resolve scores, commit).
#define STEP(d_, IN, OUT) { \
    const int c = (d_) - r; \
    int snb = __shfl_up(sme, 1); \
    float px = pnx##IN, py = pny##IN, ps = pns##IN; \
    float hcx = sel3f(sme, hx0##IN, hx1##IN, hx2##IN); \
    float hcy = sel3f(sme, hy0##IN, hy1##IN, hy2##IN); \
    float vcx = sel3f(snb, vx0##IN, vx1##IN, vx2##IN); \
    float vcy = sel3f(snb, vy0##IN, vy1##IN, vy2##IN); \
    PREFETCH((d_) + 1, OUT, px, py, vcx, vcy, hcx, hcy); \
    __builtin_amdgcn_sched_barrier(0); \
    f2u HA, HB, VA, VB; \
    HA.x = sel3f(sme, hA0##IN.x, hA1##IN.x, hA2##IN.x); \
    HA.y = sel3f(sme, hA0##IN.y, hA1##IN.y, hA2##IN.y); \
    HB.x = sel3f(sme, hB0##IN.x, hB1##IN.x, hB2##IN.x); \
    HB.y = sel3f(sme, hB0##IN.y, hB1##IN.y, hB2##IN.y); \
    VA.x = sel3f(snb, vA0##IN.x, vA1##IN.x, vA2##IN.x); \
    VA.y = sel3f(snb, vA0##IN.y, vA1##IN.y, vA2##IN.y); \
    VB.x = sel3f(snb, vB0##IN.x, vB1##IN.x, vB2##IN.x); \
    VB.y = sel3f(snb, vB0##IN.y, vB1##IN.y, vB2##IN.y); \
    float hs = score_taps(hcx, hcy, HA, HB); \
    float vs = score_taps(vcx, vcy, VA, VB); \
    bool uv = (vs > ps) && (r > 0); \
    float ux = uv ? vcx : px; \
    float uy = uv ? vcy : py; \
    float us = uv ? vs : ps; \
    bool uh = (hs > us) && (c > 0); \
    float fx = uh ? hcx : ux; \
    float fy = uh ? hcy : uy; \
    float fs = uh ? hs : us; \
    sme = uh ? 2 : (uv ? 1 : 0); \
    if ((c >= 0) && (c < 64)) { \
        const int j = dxpos ? c : 63 - c; \
        const int p = i * 64 + j; \
        lx[p] = fx; ly[p] = fy; ls[p] = fs; \
    } \
}

__global__ __launch_bounds__(512, 1) void MatchingPropagator_65180423685702_kernel(
        const float* __restrict__ raw,    // (B,2,64,64)
        const float* __restrict__ corr,   // (B,64,64,64,64)
        const float* __restrict__ noise,  // (3,B,64,64,2)
        float* __restrict__ out) {        // (B,2,64,64)
    const int b = blockIdx.x;
    const float* __restrict__ corrb = corr + (size_t)b * 64 * 64 * 4096;
    const int tid = threadIdx.x;

    __shared__ float lx[4096];
    __shared__ float ly[4096];
    __shared__ float ls[4096];

    // init: coords + memoized scores (parallel)
    for (int p = tid; p < 4096; p += 512) {
        float x = raw[(size_t)b * 8192 + p];
        float y = raw[(size_t)b * 8192 + 4096 + p];
        lx[p] = x; ly[p] = y;
        ls[p] = bsample(corrb + (size_t)p * 4096, x, y);
    }
    __syncthreads();

    const int dys[4] = {1, -1, -1, 1};
    const int dxs[4] = {1, -1, 1, -1};

#pragma unroll
    for (int k = 0; k < 4; ++k) {
        const int dy = dys[k], dx = dxs[k];
        const float fdy = (float)dy, fdx = (float)dx;
        const bool dxpos = (dx > 0);

        if (tid < 64) {
            const int r = tid;
            const int i = (dy > 0) ? r : 63 - r;
            const float* rowbase = corrb + (size_t)i * 64 * 4096;
            int sme = 0;
            BANK_DECL(_A)
            BANK_DECL(_B)

            // prologue: bank A for d=0 with all carries = (0,0)
            PREFETCH(0, _A, 0.0f, 0.0f, 0.0f, 0.0f, 0.0f, 0.0f);

#pragma unroll 1
            for (int d = 0; d < 128; d += 2) {
                STEP(d, _A, _B);
                STEP(d + 1, _B, _A);
            }
        }
        __syncthreads();

        // random search (elementwise, all 512 threads)
        if (k < 3) {
            const float* nz = noise + ((size_t)k * 2 + b) * 8192;
            for (int p = tid; p < 4096; p += 512) {
                float x = lx[p], y = ly[p], s = ls[p];
                float ex = nz[p * 2 + 0], ey = nz[p * 2 + 1];
                float nx = fmaxf(__fadd_rn(x, __fmul_rn(3.0f, ex)), 0.0f);
                float ny = fmaxf(__fadd_rn(y, __fmul_rn(3.0f, ey)), 0.0f);
                // faithful reference oddity: boundary hit overwrites BOTH channels
                if (nx >= 64.0f) { nx = 63.0f; ny = 63.0f; }
                if (ny >= 64.0f) { nx = 63.0f; ny = 63.0f; }
                float ns = bsample(corrb + (size_t)p * 4096, nx, ny);
                if (ns > __fmul_rn(1.05f, s)) {
                    lx[p] = nx; ly[p] = ny; ls[p] = ns;
                }
            }
            __syncthreads();
        }
    }

    // output: (B,2,H,W)
    for (int p = tid; p < 4096; p += 512) {
        out[(size_t)b * 8192 + p] = lx[p];
        out[(size_t)b * 8192 + 4096 + p] = ly[p];
    }
}

extern "C" void kernel_launch(void* const* d_in, const int* in_sizes, int n_in,
                              void* d_out, int out_size, void* d_ws, size_t ws_size,
                              hipStream_t stream) {
    const float* raw   = (const float*)d_in[0];
    const float* corr  = (const float*)d_in[1];
    const float* noise = (const float*)d_in[2];
    float* out = (float*)d_out;
    (void)in_sizes; (void)n_in; (void)out_size; (void)d_ws; (void)ws_size;
    MatchingPropagator_65180423685702_kernel<<<2, 512, 0, stream>>>(raw, corr, noise, out);
}